// Round 1
// baseline (103.091 us; speedup 1.0000x reference)
//
#include <hip/hip_runtime.h>
#include <hip/hip_bf16.h>
#include <math.h>

// Problem: VOCAB=50257, E=64, D=16, DK=32, B*S=65536, membership p=0.05
#define EDIM 64
#define DDOM 16
#define DKDIM 32
#define NTHREADS 256
#define NBA 1024            // job-A blocks in prep (out = h streaming)
#define MBD 32              // blocks per domain in mlp5
#define MAXNBB 2048         // max jobB blocks (ntok <= 524288) for pfx LDS
#define EXCL_BIT 0x40000000 // list-entry flag: token has exactly one domain

// ws layout: int blkcnt[16][nbb] @0 | int lists[16][ntok] @lists_off
//
// R8: memset-free allocation (fixed per-block segments + mlp5 prefix scan),
// exclusive-token fast path (jobA skips 1-domain rows; mlp5 plain-stores
// h+0.1c for them, reading h from tab = L1-hot from the A-frag gather).
// mlp5 unchanged otherwise: weights in MFMA B-fragments loaded once/wave,
// per 16-token group: U = H x W1 (4 mfma), gelu, LDS repack (m120 pattern),
// C = U x W2 (4 mfma), then excl-store or atomicAdd.
// Layouts (16x16x32 bf16, HW-verified): A[m=lane&15][k=quad*8+j];
// C/D col=lane&15,row=quad*4+reg; B[k=quad*8+j][n=lane&15].

typedef __attribute__((ext_vector_type(8))) short bf16x8;
typedef __attribute__((ext_vector_type(4))) float f32x4;

__device__ __forceinline__ short f2bf(float f) {   // fp32 -> bf16 bits, RNE
    unsigned u = __float_as_uint(f);
    u += 0x7FFFu + ((u >> 16) & 1u);
    return (short)(u >> 16);
}

__device__ __forceinline__ unsigned load_mask(const unsigned char* __restrict__ memb,
                                              int tok, int mcode) {
    unsigned m = 0;
    if (mcode & 1) {          // bf16 0.0/1.0
        const unsigned short* p = (const unsigned short*)memb + (size_t)tok * DDOM;
        #pragma unroll
        for (int d = 0; d < DDOM; ++d) m |= (unsigned)(p[d] != 0) << d;
    } else if (mcode & 2) {   // uint8
        const unsigned char* p = memb + (size_t)tok * DDOM;
        #pragma unroll
        for (int d = 0; d < DDOM; ++d) m |= (unsigned)(p[d] != 0) << d;
    } else {                  // int32
        const int* p = (const int*)memb + (size_t)tok * DDOM;
        #pragma unroll
        for (int d = 0; d < DDOM; ++d) m |= (unsigned)(p[d] != 0) << d;
    }
    return m;
}

// ---------------------------------------------------------------------------
__global__ void prep_kernel(const int* __restrict__ x,
                            const float* __restrict__ tab,
                            const unsigned char* __restrict__ memb,
                            float* __restrict__ out,
                            int* __restrict__ blkcnt,   // [16][nbb], plain stores
                            int* __restrict__ lists,    // [16][ntok], segmented
                            int ntok, int nbb)
{
    const int thr  = threadIdx.x;
    const int bid  = blockIdx.x;
    const int lane = thr & 63;

    // membership dtype detect (first 4096 B; membership >= 804112 B: in-bounds)
    __shared__ int det;
    __shared__ int lcnt[DDOM];
    if (thr == 0) det = 0;
    if (thr < DDOM) lcnt[thr] = 0;
    __syncthreads();
    {
        const uint4 vv = ((const uint4*)memb)[thr];
        unsigned int w[4] = {vv.x, vv.y, vv.z, vv.w};
        int saw = 0;
        #pragma unroll
        for (int dw = 0; dw < 4; ++dw)
            #pragma unroll
            for (int b = 0; b < 4; ++b) {
                unsigned int byte = (w[dw] >> (8 * b)) & 0xFFu;
                if (byte > 1u) saw |= 1;            // bf16 signature bytes
                if (byte == 1u && b != 0) saw |= 2; // '1' at offset %4 != 0 -> u8
            }
        if (saw) atomicOr(&det, saw);
    }
    __syncthreads();
    const int mcode = det;

    if (bid < NBA) {
        // ---- job A: out = embed_table[x], SKIPPING exclusive (1-domain) rows
        // (mlp5 writes those rows in full with plain stores).
        const int nf4 = ntok * 16;
        for (int i = bid * NTHREADS + thr; i < nf4; i += NBA * NTHREADS) {
            int t = i >> 4, s = i & 15;
            int tok = x[t];
            // one membership load per 16-lane group (groups are 16-aligned:
            // stride NBA*NTHREADS and base bid*NTHREADS are multiples of 256)
            unsigned mm = 0;
            if ((lane & 15) == 0) mm = load_mask(memb, tok, mcode);
            mm = __shfl(mm, lane & 48, 64);
            if (!(mm && !(mm & (mm - 1)))) {        // write unless popcount==1
                float4 hv = ((const float4*)(tab + (size_t)tok * EDIM))[s];
                ((float4*)(out + (size_t)t * EDIM))[s] = hv;
            }
        }
        return;
    }

    // ---- job B: per-domain compaction into FIXED per-block segments.
    // No global atomics, no pre-zeroed memory needed.
    const int bi = bid - NBA;
    const int t  = bi * NTHREADS + thr;
    unsigned m = 0;
    if (t < ntok) m = load_mask(memb, x[t], mcode);
    int entry = t;
    if (m && !(m & (m - 1))) entry |= EXCL_BIT;     // exactly one domain
    #pragma unroll
    for (int d = 0; d < DDOM; ++d)
        if ((m >> d) & 1u) {
            int p = atomicAdd(&lcnt[d], 1);         // LDS-only atomic
            lists[(size_t)d * ntok + bi * NTHREADS + p] = entry;
        }
    __syncthreads();
    if (thr < DDOM) blkcnt[(size_t)thr * nbb + bi] = lcnt[thr];
}

// ---------------------------------------------------------------------------
// mlp5: grid = 16 domains x 32 blocks, 256 threads (4 waves), 2 blocks/CU.
// Prologue: prefix-scan blkcnt[d][*] in LDS (shfl scan, 2 barriers/chunk).
// Group loop: binary-search pfx to map compact index -> (segment, offset).
// ---------------------------------------------------------------------------
__global__ __launch_bounds__(256, 2) void mlp5_kernel(
    const int* __restrict__ lists,
    const int* __restrict__ blkcnt,
    const int* __restrict__ x,
    const float* __restrict__ tab,
    const float* __restrict__ W1,   // [D][E][DK]
    const float* __restrict__ W2,   // [D][DK][E]
    float* __restrict__ out,
    int ntok, int nbb)
{
    __shared__ float u_lds[4][16][36];   // per-wave U repack, padded, 9.2 KB
    __shared__ int   pfx[MAXNBB + 1];    // exclusive prefix of segment counts
    __shared__ int   wsum[4];

    const int thr = threadIdx.x, lane = thr & 63, wid = thr >> 6;
    const int d    = blockIdx.x >> 5;
    const int blk  = blockIdx.x & (MBD - 1);
    const int col  = lane & 15;   // n-index inside a 16-wide tile
    const int quad = lane >> 4;   // k-index base = quad*8

    // ---- prefix scan of per-segment counts (chunks of 256) ----
    int carry = 0;
    for (int c0 = 0; c0 < nbb; c0 += NTHREADS) {
        int i = c0 + thr;
        int v = (i < nbb) ? blkcnt[(size_t)d * nbb + i] : 0;
        int s = v;
        #pragma unroll
        for (int off = 1; off < 64; off <<= 1) {
            int a = __shfl_up(s, off, 64);
            if (lane >= off) s += a;
        }
        if (lane == 63) wsum[wid] = s;
        __syncthreads();
        int wadd = 0;
        #pragma unroll
        for (int w = 0; w < 4; ++w) if (w < wid) wadd += wsum[w];
        if (i < nbb) pfx[i] = carry + wadd + (s - v);   // exclusive prefix
        carry += wsum[0] + wsum[1] + wsum[2] + wsum[3];
        __syncthreads();
    }
    const int n = carry;                 // total tokens in this domain
    if (n == 0) return;

    // ---- weight fragments, once per wave. B[k=quad*8+j][n=col] ----
    const float* __restrict__ w1g = W1 + d * (EDIM * DKDIM);  // [e][ko]
    const float* __restrict__ w2g = W2 + d * (DKDIM * EDIM);  // [k][e]
    bf16x8 w1f[2][2];   // [K-tile tk: e=tk*32+quad*8+j][n-half tn: ko=tn*16+col]
    #pragma unroll
    for (int tk = 0; tk < 2; ++tk)
        #pragma unroll
        for (int tn = 0; tn < 2; ++tn)
            #pragma unroll
            for (int j = 0; j < 8; ++j)
                w1f[tk][tn][j] = f2bf(w1g[(tk * 32 + quad * 8 + j) * DKDIM + tn * 16 + col]);
    bf16x8 w2f[4];      // [e-tile te: k=quad*8+j, n=e=te*16+col]
    #pragma unroll
    for (int te = 0; te < 4; ++te)
        #pragma unroll
        for (int j = 0; j < 8; ++j)
            w2f[te][j] = f2bf(w2g[(quad * 8 + j) * EDIM + te * 16 + col]);

    const int ngrp = (n + 15) >> 4;
    for (int g = blk * 4 + wid; g < ngrp; g += MBD * 4) {
        const int base = g * 16;
        // lane carries token row m=col of this group
        const int ti = base + col;
        const bool v = ti < n;
        int entry = 0;
        if (v) {
            int lo = 0, hi = nbb;       // find segment: pfx[lo] <= ti < pfx[lo+1]
            while (hi - lo > 1) {
                int mid = (lo + hi) >> 1;
                if (pfx[mid] <= ti) lo = mid; else hi = mid;
            }
            entry = lists[(size_t)d * ntok + lo * NTHREADS + (ti - pfx[lo])];
        }
        const int pos   = entry & 0x3FFFFFFF;
        const int tokid = v ? x[pos] : 0;

        // A-fragments of h: A[m=col][k=e=tk*32+quad*8+j]
        const float* __restrict__ hrow = tab + (size_t)tokid * EDIM;
        bf16x8 ha[2];
        #pragma unroll
        for (int tk = 0; tk < 2; ++tk) {
            f32x4 a = *(const f32x4*)(hrow + tk * 32 + quad * 8);
            f32x4 b = *(const f32x4*)(hrow + tk * 32 + quad * 8 + 4);
            ha[tk][0] = f2bf(a.x); ha[tk][1] = f2bf(a.y);
            ha[tk][2] = f2bf(a.z); ha[tk][3] = f2bf(a.w);
            ha[tk][4] = f2bf(b.x); ha[tk][5] = f2bf(b.y);
            ha[tk][6] = f2bf(b.z); ha[tk][7] = f2bf(b.w);
        }

        // hoist per-row entry/token (4+4 shfls instead of 16)
        int ent_r[4], tok_r[4];
        #pragma unroll
        for (int r = 0; r < 4; ++r) {
            int mrow = quad * 4 + r;
            ent_r[r] = __shfl(entry, mrow, 64);
            tok_r[r] = __shfl(tokid, mrow, 64);
        }

        // ---- step1: U[16 tok x 32 ko], 2 n-halves x K=64 (2 mfma each) ----
        #pragma unroll
        for (int tn = 0; tn < 2; ++tn) {
            f32x4 acc = {0.f, 0.f, 0.f, 0.f};
            acc = __builtin_amdgcn_mfma_f32_16x16x32_bf16(ha[0], w1f[0][tn], acc, 0, 0, 0);
            acc = __builtin_amdgcn_mfma_f32_16x16x32_bf16(ha[1], w1f[1][tn], acc, 0, 0, 0);
            // gelu on D-frag (D[m=quad*4+r][ko=tn*16+col]) -> u_lds[m][ko]
            #pragma unroll
            for (int r = 0; r < 4; ++r) {
                float u = acc[r];
                float gg, au = fabsf(u);
                if (__builtin_expect(au > 0.35f, 0)) {
                    gg = 0.5f * u * (1.f + erff(u * 0.70710678118654752f));
                } else {
                    float uu = u * u;
                    gg = u * (0.5f + u * (0.3989422804f + uu * (-0.06649038f + uu * 0.00997356f)));
                }
                u_lds[wid][quad * 4 + r][tn * 16 + col] = gg;
            }
        }

        // ---- repack U: D-layout -> A-layout (same-wave RAW via in-order DS) ----
        bf16x8 ua;
        {
            const float* __restrict__ up = &u_lds[wid][col][quad * 8];
            f32x4 a = *(const f32x4*)(up);
            f32x4 b = *(const f32x4*)(up + 4);
            ua[0] = f2bf(a.x); ua[1] = f2bf(a.y); ua[2] = f2bf(a.z); ua[3] = f2bf(a.w);
            ua[4] = f2bf(b.x); ua[5] = f2bf(b.y); ua[6] = f2bf(b.z); ua[7] = f2bf(b.w);
        }

        // ---- step2: C[16 tok x 64 e] = U x W2; excl rows: plain store of
        // h+0.1c (h re-read from tab = L1-hot); shared rows: atomicAdd. ----
        #pragma unroll
        for (int te = 0; te < 4; ++te) {
            f32x4 acc = {0.f, 0.f, 0.f, 0.f};
            acc = __builtin_amdgcn_mfma_f32_16x16x32_bf16(ua, w2f[te], acc, 0, 0, 0);
            #pragma unroll
            for (int r = 0; r < 4; ++r) {
                int mrow = quad * 4 + r;
                if (base + mrow < n) {
                    int e = ent_r[r];
                    float val = 0.1f * acc[r];
                    size_t o = (size_t)(e & 0x3FFFFFFF) * EDIM + te * 16 + col;
                    if (e & EXCL_BIT) {
                        out[o] = tab[(size_t)tok_r[r] * EDIM + te * 16 + col] + val;
                    } else {
                        atomicAdd(&out[o], val);
                    }
                }
            }
        }
    }
}

// ---------------------------------------------------------------------------
// Fallback (ws too small / ntok too large): round-2 fused kernel, known-correct.
// ---------------------------------------------------------------------------
__global__ __launch_bounds__(256, 4) void domain_embed_fused(
    const int* __restrict__ x, const float* __restrict__ tab,
    const float* __restrict__ W1, const float* __restrict__ W2,
    const unsigned char* __restrict__ memb, float* __restrict__ out, int ntok)
{
    __shared__ float h_lds[32][EDIM];
    __shared__ float corr[32][EDIM];
    __shared__ int   tok_lds[32];
    __shared__ unsigned int mask_lds[32];
    __shared__ unsigned short pairs[32 * DDOM];
    __shared__ int npairs;
    __shared__ int det_wave[4];
    const int thr = threadIdx.x, lane = thr & 63, wid = thr >> 6;
    const int tok0 = blockIdx.x * 32;
    if (thr < 32) { int t = tok0 + thr; tok_lds[thr] = (t < ntok) ? x[t] : 0; }
    #pragma unroll
    for (int i = 0; i < 8; ++i) ((float*)corr)[thr + i * 256] = 0.f;
    if (thr == 0) npairs = 0;
    {
        const uint4 v = ((const uint4*)memb)[thr];
        unsigned int w[4] = {v.x, v.y, v.z, v.w};
        bool sawbf = false, saw8 = false;
        #pragma unroll
        for (int dw = 0; dw < 4; ++dw)
            #pragma unroll
            for (int b = 0; b < 4; ++b) {
                unsigned int byte = (w[dw] >> (8 * b)) & 0xFFu;
                if (byte > 1u) sawbf = true;
                if (byte == 1u && b != 0) saw8 = true;
            }
        unsigned long long b1 = __ballot(sawbf), b2 = __ballot(saw8);
        if (lane == 0) det_wave[wid] = (b1 ? 1 : 0) | (b2 ? 2 : 0);
    }
    __syncthreads();
    const int mcode = det_wave[0] | det_wave[1] | det_wave[2] | det_wave[3];
    #pragma unroll
    for (int pass = 0; pass < 2; ++pass) {
        int row = pass * 16 + (thr >> 4);
        const float4 hv = ((const float4*)(tab + (size_t)tok_lds[row] * EDIM))[thr & 15];
        ((float4*)&h_lds[row][0])[thr & 15] = hv;
    }
    if (thr < 32) {
        int tokid = tok_lds[thr];
        unsigned int m = 0;
        if (mcode & 1) { const unsigned short* p = (const unsigned short*)memb + (size_t)tokid * DDOM;
            #pragma unroll
            for (int d = 0; d < DDOM; ++d) m |= (unsigned)(p[d] != 0) << d;
        } else if (mcode & 2) { const unsigned char* p = memb + (size_t)tokid * DDOM;
            #pragma unroll
            for (int d = 0; d < DDOM; ++d) m |= (unsigned)(p[d] != 0) << d;
        } else { const int* p = (const int*)memb + (size_t)tokid * DDOM;
            #pragma unroll
            for (int d = 0; d < DDOM; ++d) m |= (unsigned)(p[d] != 0) << d;
        }
        mask_lds[thr] = m;
    }
    __syncthreads();
    for (int cc = thr; cc < 32 * DDOM; cc += 256) {
        int t = cc >> 4, d = cc & 15;
        if ((mask_lds[t] >> d) & 1u) { int idx = atomicAdd(&npairs, 1); pairs[idx] = (unsigned short)cc; }
    }
    __syncthreads();
    const int np = npairs, k = lane & 31, p = lane >> 5;
    for (int pi = wid; pi < np; pi += 4) {
        int cc = pairs[pi], t = cc >> 4, d = cc & 15;
        const float* __restrict__ w1 = W1 + d * (EDIM * DKDIM);
        float u = 0.f;
        #pragma unroll
        for (int j4 = 0; j4 < 8; ++j4) {
            float4 hv = ((const float4*)&h_lds[t][p * 32])[j4];
            int e = p * 32 + j4 * 4;
            u = fmaf(hv.x, w1[(e + 0) * DKDIM + k], u);
            u = fmaf(hv.y, w1[(e + 1) * DKDIM + k], u);
            u = fmaf(hv.z, w1[(e + 2) * DKDIM + k], u);
            u = fmaf(hv.w, w1[(e + 3) * DKDIM + k], u);
        }
        u += __shfl_xor(u, 32, 64);
        float gg, au = fabsf(u);
        if (__builtin_expect(__ballot(au > 0.35f) != 0ull, 0))
            gg = 0.5f * u * (1.f + erff(u * 0.70710678118654752f));
        else { float uu = u * u; gg = u * (0.5f + u * (0.3989422804f + uu * (-0.06649038f + uu * 0.00997356f))); }
        const float* __restrict__ w2 = W2 + d * (DKDIM * EDIM);
        float cp = 0.f;
        #pragma unroll
        for (int kk = 0; kk < DKDIM; ++kk) cp = fmaf(__shfl(gg, kk, 64), w2[kk * EDIM + lane], cp);
        atomicAdd(&corr[t][lane], cp);
    }
    __syncthreads();
    #pragma unroll
    for (int pass = 0; pass < 2; ++pass) {
        int row = pass * 16 + (thr >> 4), gt = tok0 + row;
        if (gt < ntok) {
            float4 hv = ((const float4*)&h_lds[row][0])[thr & 15];
            float4 cv = ((const float4*)&corr[row][0])[thr & 15];
            float4 o = {hv.x + 0.1f * cv.x, hv.y + 0.1f * cv.y, hv.z + 0.1f * cv.z, hv.w + 0.1f * cv.w};
            ((float4*)(out + (size_t)gt * EDIM))[thr & 15] = o;
        }
    }
}

extern "C" void kernel_launch(void* const* d_in, const int* in_sizes, int n_in,
                              void* d_out, int out_size, void* d_ws, size_t ws_size,
                              hipStream_t stream) {
    const int*   x    = (const int*)  d_in[0];
    const float* tab  = (const float*)d_in[1];
    const float* W1   = (const float*)d_in[2];
    const float* W2   = (const float*)d_in[3];
    const unsigned char* memb = (const unsigned char*)d_in[4];
    float* out = (float*)d_out;
    const int ntok = in_sizes[0];

    // ws: blkcnt[16][nbb] @0 | lists[16][ntok] @lists_off  (no memset needed:
    // blkcnt fully written by jobB, unused list slots never read)
    const int nbb = (ntok + NTHREADS - 1) / NTHREADS;
    const size_t lists_off = ((size_t)DDOM * nbb * sizeof(int) + 255) & ~(size_t)255;
    const size_t need      = lists_off + (size_t)DDOM * (size_t)ntok * sizeof(int);
    if (ws_size >= need && nbb <= MAXNBB) {
        int* blkcnt = (int*)d_ws;
        int* lists  = (int*)((char*)d_ws + lists_off);
        prep_kernel<<<NBA + nbb, NTHREADS, 0, stream>>>(
            x, tab, memb, out, blkcnt, lists, ntok, nbb);
        mlp5_kernel<<<DDOM * MBD, NTHREADS, 0, stream>>>(
            lists, blkcnt, x, tab, W1, W2, out, ntok, nbb);
    } else {
        const int blocks = (ntok + 31) / 32;
        domain_embed_fused<<<blocks, NTHREADS, 0, stream>>>(x, tab, W1, W2, memb, out, ntok);
    }
}

// Round 2
// 96.885 us; speedup vs baseline: 1.0641x; 1.0641x over previous
//
#include <hip/hip_runtime.h>
#include <hip/hip_bf16.h>
#include <math.h>

// Problem: VOCAB=50257, E=64, D=16, DK=32, B*S=65536, membership p=0.05
#define EDIM 64
#define DDOM 16
#define DKDIM 32
#define NTHREADS 256
#define NBA 1024            // job-A blocks in prep (out = h streaming)
#define MBD 32              // blocks per domain in mlp5
#define MAXNBB 2048         // max jobB blocks (ntok <= 524288) for pfx LDS

// ws layout: int blkcnt[16][nbb] @0 | int lists[16][ntok] @lists_off
//
// R9 = R0 semantics + memset-free allocation ONLY (R8 post-mortem: the
// exclusive-token skip gapped jobA's write stream and added a random
// membership gather to the hottest loop -> reverted; segmented allocation
// kept: jobB writes counts with plain stores into fixed per-block segments,
// mlp5 prefix-scans them in LDS and binary-searches per 16-token group.
// mlp5 core unchanged: weights in MFMA B-fragments loaded once per wave,
// per 16-token group: U = H x W1 (4 mfma), gelu, LDS repack (m120 pattern),
// C = U x W2 (4 mfma), atomicAdd 0.1*corr (fire-and-forget, latency-hidden).
// Layouts (16x16x32 bf16, HW-verified): A[m=lane&15][k=quad*8+j];
// C/D col=lane&15,row=quad*4+reg; B[k=quad*8+j][n=lane&15].

typedef __attribute__((ext_vector_type(8))) short bf16x8;
typedef __attribute__((ext_vector_type(4))) float f32x4;

__device__ __forceinline__ short f2bf(float f) {   // fp32 -> bf16 bits, RNE
    unsigned u = __float_as_uint(f);
    u += 0x7FFFu + ((u >> 16) & 1u);
    return (short)(u >> 16);
}

__device__ __forceinline__ unsigned load_mask(const unsigned char* __restrict__ memb,
                                              int tok, int mcode) {
    unsigned m = 0;
    if (mcode & 1) {          // bf16 0.0/1.0
        const unsigned short* p = (const unsigned short*)memb + (size_t)tok * DDOM;
        #pragma unroll
        for (int d = 0; d < DDOM; ++d) m |= (unsigned)(p[d] != 0) << d;
    } else if (mcode & 2) {   // uint8
        const unsigned char* p = memb + (size_t)tok * DDOM;
        #pragma unroll
        for (int d = 0; d < DDOM; ++d) m |= (unsigned)(p[d] != 0) << d;
    } else {                  // int32
        const int* p = (const int*)memb + (size_t)tok * DDOM;
        #pragma unroll
        for (int d = 0; d < DDOM; ++d) m |= (unsigned)(p[d] != 0) << d;
    }
    return m;
}

// ---------------------------------------------------------------------------
__global__ void prep_kernel(const int* __restrict__ x,
                            const float* __restrict__ tab,
                            const unsigned char* __restrict__ memb,
                            float* __restrict__ out,
                            int* __restrict__ blkcnt,   // [16][nbb], plain stores
                            int* __restrict__ lists,    // [16][ntok], segmented
                            int ntok, int nbb)
{
    const int thr = threadIdx.x;
    const int bid = blockIdx.x;
    if (bid < NBA) {
        // ---- job A: out = embed_table[x]  (coalesced float4 gather-stream)
        const int nf4 = ntok * 16;
        for (int i = bid * NTHREADS + thr; i < nf4; i += NBA * NTHREADS) {
            int t = i >> 4, s = i & 15;
            int tok = x[t];
            float4 hv = ((const float4*)(tab + (size_t)tok * EDIM))[s];
            ((float4*)(out + (size_t)t * EDIM))[s] = hv;
        }
        return;
    }

    // ---- job B: membership dtype detect + per-domain compaction into
    // FIXED per-block segments (no global atomics, no pre-zeroed memory).
    __shared__ int det;
    __shared__ int lcnt[DDOM];
    if (thr == 0) det = 0;
    if (thr < DDOM) lcnt[thr] = 0;
    __syncthreads();
    {   // scan first 4096 bytes (membership >= 804112 elements >= 1 B: in-bounds)
        const uint4 vv = ((const uint4*)memb)[thr];
        unsigned int w[4] = {vv.x, vv.y, vv.z, vv.w};
        int saw = 0;
        #pragma unroll
        for (int dw = 0; dw < 4; ++dw)
            #pragma unroll
            for (int b = 0; b < 4; ++b) {
                unsigned int byte = (w[dw] >> (8 * b)) & 0xFFu;
                if (byte > 1u) saw |= 1;            // bf16 signature bytes
                if (byte == 1u && b != 0) saw |= 2; // '1' at offset %4 != 0 -> u8
            }
        if (saw) atomicOr(&det, saw);
    }
    __syncthreads();
    const int mcode = det;

    const int bi = bid - NBA;
    const int t  = bi * NTHREADS + thr;
    unsigned m = 0;
    if (t < ntok) m = load_mask(memb, x[t], mcode);
    #pragma unroll
    for (int d = 0; d < DDOM; ++d)
        if ((m >> d) & 1u) {
            int p = atomicAdd(&lcnt[d], 1);         // LDS-only atomic
            lists[(size_t)d * ntok + bi * NTHREADS + p] = t;   // position
        }
    __syncthreads();
    if (thr < DDOM) blkcnt[(size_t)thr * nbb + bi] = lcnt[thr];
}

// ---------------------------------------------------------------------------
// mlp5: grid = 16 domains x 32 blocks, 256 threads (4 waves), 2 blocks/CU.
// Prologue: prefix-scan blkcnt[d][*] in LDS (shfl scan, 2 barriers/chunk).
// Group loop: binary-search pfx to map compact index -> (segment, offset).
// ---------------------------------------------------------------------------
__global__ __launch_bounds__(256, 2) void mlp5_kernel(
    const int* __restrict__ lists,
    const int* __restrict__ blkcnt,
    const int* __restrict__ x,
    const float* __restrict__ tab,
    const float* __restrict__ W1,   // [D][E][DK]
    const float* __restrict__ W2,   // [D][DK][E]
    float* __restrict__ out,
    int ntok, int nbb)
{
    __shared__ float u_lds[4][16][36];   // per-wave U repack, padded, 9.2 KB
    __shared__ int   pfx[MAXNBB + 1];    // exclusive prefix of segment counts
    __shared__ int   wsum[4];

    const int thr = threadIdx.x, lane = thr & 63, wid = thr >> 6;
    const int d    = blockIdx.x >> 5;
    const int blk  = blockIdx.x & (MBD - 1);
    const int col  = lane & 15;   // n-index inside a 16-wide tile
    const int quad = lane >> 4;   // k-index base = quad*8

    // ---- prefix scan of per-segment counts (chunks of 256) ----
    int carry = 0;
    for (int c0 = 0; c0 < nbb; c0 += NTHREADS) {
        int i = c0 + thr;
        int v = (i < nbb) ? blkcnt[(size_t)d * nbb + i] : 0;
        int s = v;
        #pragma unroll
        for (int off = 1; off < 64; off <<= 1) {
            int a = __shfl_up(s, off, 64);
            if (lane >= off) s += a;
        }
        if (lane == 63) wsum[wid] = s;
        __syncthreads();
        int wadd = 0;
        #pragma unroll
        for (int w = 0; w < 4; ++w) if (w < wid) wadd += wsum[w];
        if (i < nbb) pfx[i] = carry + wadd + (s - v);   // exclusive prefix
        carry += wsum[0] + wsum[1] + wsum[2] + wsum[3];
        __syncthreads();
    }
    const int n = carry;                 // total tokens in this domain
    if (n == 0) return;

    // ---- weight fragments, once per wave. B[k=quad*8+j][n=col] ----
    const float* __restrict__ w1g = W1 + d * (EDIM * DKDIM);  // [e][ko]
    const float* __restrict__ w2g = W2 + d * (DKDIM * EDIM);  // [k][e]
    bf16x8 w1f[2][2];   // [K-tile tk: e=tk*32+quad*8+j][n-half tn: ko=tn*16+col]
    #pragma unroll
    for (int tk = 0; tk < 2; ++tk)
        #pragma unroll
        for (int tn = 0; tn < 2; ++tn)
            #pragma unroll
            for (int j = 0; j < 8; ++j)
                w1f[tk][tn][j] = f2bf(w1g[(tk * 32 + quad * 8 + j) * DKDIM + tn * 16 + col]);
    bf16x8 w2f[4];      // [e-tile te: k=quad*8+j, n=e=te*16+col]
    #pragma unroll
    for (int te = 0; te < 4; ++te)
        #pragma unroll
        for (int j = 0; j < 8; ++j)
            w2f[te][j] = f2bf(w2g[(quad * 8 + j) * EDIM + te * 16 + col]);

    const int ngrp = (n + 15) >> 4;
    for (int g = blk * 4 + wid; g < ngrp; g += MBD * 4) {
        const int base = g * 16;
        // lane carries token row m=col of this group
        const int ti = base + col;
        const bool v = ti < n;
        int pos = 0;
        if (v) {
            int lo = 0, hi = nbb;       // find segment: pfx[lo] <= ti < pfx[lo+1]
            while (hi - lo > 1) {
                int mid = (lo + hi) >> 1;
                if (pfx[mid] <= ti) lo = mid; else hi = mid;
            }
            pos = lists[(size_t)d * ntok + lo * NTHREADS + (ti - pfx[lo])];
        }
        const int tokid = v ? x[pos] : 0;

        // A-fragments of h: A[m=col][k=e=tk*32+quad*8+j]
        const float* __restrict__ hrow = tab + (size_t)tokid * EDIM;
        bf16x8 ha[2];
        #pragma unroll
        for (int tk = 0; tk < 2; ++tk) {
            f32x4 a = *(const f32x4*)(hrow + tk * 32 + quad * 8);
            f32x4 b = *(const f32x4*)(hrow + tk * 32 + quad * 8 + 4);
            ha[tk][0] = f2bf(a.x); ha[tk][1] = f2bf(a.y);
            ha[tk][2] = f2bf(a.z); ha[tk][3] = f2bf(a.w);
            ha[tk][4] = f2bf(b.x); ha[tk][5] = f2bf(b.y);
            ha[tk][6] = f2bf(b.z); ha[tk][7] = f2bf(b.w);
        }

        // hoist per-row pos (4 shfls instead of 16 in the store loop)
        int pos_r[4];
        #pragma unroll
        for (int r = 0; r < 4; ++r) pos_r[r] = __shfl(pos, quad * 4 + r, 64);

        // ---- step1: U[16 tok x 32 ko], 2 n-halves x K=64 (2 mfma each) ----
        #pragma unroll
        for (int tn = 0; tn < 2; ++tn) {
            f32x4 acc = {0.f, 0.f, 0.f, 0.f};
            acc = __builtin_amdgcn_mfma_f32_16x16x32_bf16(ha[0], w1f[0][tn], acc, 0, 0, 0);
            acc = __builtin_amdgcn_mfma_f32_16x16x32_bf16(ha[1], w1f[1][tn], acc, 0, 0, 0);
            // gelu on D-frag (D[m=quad*4+r][ko=tn*16+col]) -> u_lds[m][ko]
            #pragma unroll
            for (int r = 0; r < 4; ++r) {
                float u = acc[r];
                float gg, au = fabsf(u);
                if (__builtin_expect(au > 0.35f, 0)) {
                    gg = 0.5f * u * (1.f + erff(u * 0.70710678118654752f));
                } else {
                    float uu = u * u;
                    gg = u * (0.5f + u * (0.3989422804f + uu * (-0.06649038f + uu * 0.00997356f)));
                }
                u_lds[wid][quad * 4 + r][tn * 16 + col] = gg;
            }
        }

        // ---- repack U: D-layout -> A-layout (same-wave RAW via in-order DS) ----
        bf16x8 ua;
        {
            const float* __restrict__ up = &u_lds[wid][col][quad * 8];
            f32x4 a = *(const f32x4*)(up);
            f32x4 b = *(const f32x4*)(up + 4);
            ua[0] = f2bf(a.x); ua[1] = f2bf(a.y); ua[2] = f2bf(a.z); ua[3] = f2bf(a.w);
            ua[4] = f2bf(b.x); ua[5] = f2bf(b.y); ua[6] = f2bf(b.z); ua[7] = f2bf(b.w);
        }

        // ---- step2: C[16 tok x 64 e] = U x W2; atomicAdd 0.1*corr ----
        #pragma unroll
        for (int te = 0; te < 4; ++te) {
            f32x4 acc = {0.f, 0.f, 0.f, 0.f};
            acc = __builtin_amdgcn_mfma_f32_16x16x32_bf16(ua, w2f[te], acc, 0, 0, 0);
            #pragma unroll
            for (int r = 0; r < 4; ++r) {
                if (base + quad * 4 + r < n) {
                    atomicAdd(&out[(size_t)pos_r[r] * EDIM + te * 16 + col],
                              0.1f * acc[r]);
                }
            }
        }
    }
}

// ---------------------------------------------------------------------------
// Fallback (ws too small / ntok too large): round-2 fused kernel, known-correct.
// ---------------------------------------------------------------------------
__global__ __launch_bounds__(256, 4) void domain_embed_fused(
    const int* __restrict__ x, const float* __restrict__ tab,
    const float* __restrict__ W1, const float* __restrict__ W2,
    const unsigned char* __restrict__ memb, float* __restrict__ out, int ntok)
{
    __shared__ float h_lds[32][EDIM];
    __shared__ float corr[32][EDIM];
    __shared__ int   tok_lds[32];
    __shared__ unsigned int mask_lds[32];
    __shared__ unsigned short pairs[32 * DDOM];
    __shared__ int npairs;
    __shared__ int det_wave[4];
    const int thr = threadIdx.x, lane = thr & 63, wid = thr >> 6;
    const int tok0 = blockIdx.x * 32;
    if (thr < 32) { int t = tok0 + thr; tok_lds[thr] = (t < ntok) ? x[t] : 0; }
    #pragma unroll
    for (int i = 0; i < 8; ++i) ((float*)corr)[thr + i * 256] = 0.f;
    if (thr == 0) npairs = 0;
    {
        const uint4 v = ((const uint4*)memb)[thr];
        unsigned int w[4] = {v.x, v.y, v.z, v.w};
        bool sawbf = false, saw8 = false;
        #pragma unroll
        for (int dw = 0; dw < 4; ++dw)
            #pragma unroll
            for (int b = 0; b < 4; ++b) {
                unsigned int byte = (w[dw] >> (8 * b)) & 0xFFu;
                if (byte > 1u) sawbf = true;
                if (byte == 1u && b != 0) saw8 = true;
            }
        unsigned long long b1 = __ballot(sawbf), b2 = __ballot(saw8);
        if (lane == 0) det_wave[wid] = (b1 ? 1 : 0) | (b2 ? 2 : 0);
    }
    __syncthreads();
    const int mcode = det_wave[0] | det_wave[1] | det_wave[2] | det_wave[3];
    #pragma unroll
    for (int pass = 0; pass < 2; ++pass) {
        int row = pass * 16 + (thr >> 4);
        const float4 hv = ((const float4*)(tab + (size_t)tok_lds[row] * EDIM))[thr & 15];
        ((float4*)&h_lds[row][0])[thr & 15] = hv;
    }
    if (thr < 32) {
        int tokid = tok_lds[thr];
        unsigned int m = 0;
        if (mcode & 1) { const unsigned short* p = (const unsigned short*)memb + (size_t)tokid * DDOM;
            #pragma unroll
            for (int d = 0; d < DDOM; ++d) m |= (unsigned)(p[d] != 0) << d;
        } else if (mcode & 2) { const unsigned char* p = memb + (size_t)tokid * DDOM;
            #pragma unroll
            for (int d = 0; d < DDOM; ++d) m |= (unsigned)(p[d] != 0) << d;
        } else { const int* p = (const int*)memb + (size_t)tokid * DDOM;
            #pragma unroll
            for (int d = 0; d < DDOM; ++d) m |= (unsigned)(p[d] != 0) << d;
        }
        mask_lds[thr] = m;
    }
    __syncthreads();
    for (int cc = thr; cc < 32 * DDOM; cc += 256) {
        int t = cc >> 4, d = cc & 15;
        if ((mask_lds[t] >> d) & 1u) { int idx = atomicAdd(&npairs, 1); pairs[idx] = (unsigned short)cc; }
    }
    __syncthreads();
    const int np = npairs, k = lane & 31, p = lane >> 5;
    for (int pi = wid; pi < np; pi += 4) {
        int cc = pairs[pi], t = cc >> 4, d = cc & 15;
        const float* __restrict__ w1 = W1 + d * (EDIM * DKDIM);
        float u = 0.f;
        #pragma unroll
        for (int j4 = 0; j4 < 8; ++j4) {
            float4 hv = ((const float4*)&h_lds[t][p * 32])[j4];
            int e = p * 32 + j4 * 4;
            u = fmaf(hv.x, w1[(e + 0) * DKDIM + k], u);
            u = fmaf(hv.y, w1[(e + 1) * DKDIM + k], u);
            u = fmaf(hv.z, w1[(e + 2) * DKDIM + k], u);
            u = fmaf(hv.w, w1[(e + 3) * DKDIM + k], u);
        }
        u += __shfl_xor(u, 32, 64);
        float gg, au = fabsf(u);
        if (__builtin_expect(__ballot(au > 0.35f) != 0ull, 0))
            gg = 0.5f * u * (1.f + erff(u * 0.70710678118654752f));
        else { float uu = u * u; gg = u * (0.5f + u * (0.3989422804f + uu * (-0.06649038f + uu * 0.00997356f))); }
        const float* __restrict__ w2 = W2 + d * (DKDIM * EDIM);
        float cp = 0.f;
        #pragma unroll
        for (int kk = 0; kk < DKDIM; ++kk) cp = fmaf(__shfl(gg, kk, 64), w2[kk * EDIM + lane], cp);
        atomicAdd(&corr[t][lane], cp);
    }
    __syncthreads();
    #pragma unroll
    for (int pass = 0; pass < 2; ++pass) {
        int row = pass * 16 + (thr >> 4), gt = tok0 + row;
        if (gt < ntok) {
            float4 hv = ((const float4*)&h_lds[row][0])[thr & 15];
            float4 cv = ((const float4*)&corr[row][0])[thr & 15];
            float4 o = {hv.x + 0.1f * cv.x, hv.y + 0.1f * cv.y, hv.z + 0.1f * cv.z, hv.w + 0.1f * cv.w};
            ((float4*)(out + (size_t)gt * EDIM))[thr & 15] = o;
        }
    }
}

extern "C" void kernel_launch(void* const* d_in, const int* in_sizes, int n_in,
                              void* d_out, int out_size, void* d_ws, size_t ws_size,
                              hipStream_t stream) {
    const int*   x    = (const int*)  d_in[0];
    const float* tab  = (const float*)d_in[1];
    const float* W1   = (const float*)d_in[2];
    const float* W2   = (const float*)d_in[3];
    const unsigned char* memb = (const unsigned char*)d_in[4];
    float* out = (float*)d_out;
    const int ntok = in_sizes[0];

    // ws: blkcnt[16][nbb] @0 | lists[16][ntok] @lists_off  (no memset needed:
    // blkcnt fully written by jobB, unused list slots never read)
    const int nbb = (ntok + NTHREADS - 1) / NTHREADS;
    const size_t lists_off = ((size_t)DDOM * nbb * sizeof(int) + 255) & ~(size_t)255;
    const size_t need      = lists_off + (size_t)DDOM * (size_t)ntok * sizeof(int);
    if (ws_size >= need && nbb <= MAXNBB) {
        int* blkcnt = (int*)d_ws;
        int* lists  = (int*)((char*)d_ws + lists_off);
        prep_kernel<<<NBA + nbb, NTHREADS, 0, stream>>>(
            x, tab, memb, out, blkcnt, lists, ntok, nbb);
        mlp5_kernel<<<DDOM * MBD, NTHREADS, 0, stream>>>(
            lists, blkcnt, x, tab, W1, W2, out, ntok, nbb);
    } else {
        const int blocks = (ntok + 31) / 32;
        domain_embed_fused<<<blocks, NTHREADS, 0, stream>>>(x, tab, W1, W2, memb, out, ntok);
    }
}